// Round 1
// baseline (8749.565 us; speedup 1.0000x reference)
//
#include <hip/hip_runtime.h>
#include <cstdint>
#include <cstddef>

#define BATCH 256
#define SEQ   512
#define DIM   1024
#define HID   2048
#define NOUT  32

// ---------------------------------------------------------------------------
// Kernel 1: G[b*T+t, h] = x[b,t,:] @ W1[:DIM, h] + b1[h]       (fp32 GEMM)
// M = 131072, K = 1024, N = 2048.  128x128 tile, BK=16, 256 thr, 8x8 microtile
// ---------------------------------------------------------------------------
#define BM 128
#define BN 128
#define BK 16

__global__ __launch_bounds__(256) void gemm_g(const float* __restrict__ A,
                                              const float* __restrict__ W1,
                                              const float* __restrict__ b1,
                                              float* __restrict__ G)
{
    constexpr int K = DIM, N = HID;
    __shared__ float As[BK][BM];   // stored transposed: As[k][m]
    __shared__ float Bs[BK][BN];

    const int tid = threadIdx.x;
    const size_t m0 = (size_t)blockIdx.x * BM;
    const int    n0 = blockIdx.y * BN;

    // A staging: each thread loads 8 floats along K (row rowA, cols kcA..kcA+7)
    const int rowA = tid >> 1;
    const int kcA  = (tid & 1) * 8;
    // B staging: each thread loads 8 consecutive floats of one W1 row
    const int kB  = tid >> 4;
    const int ncB = (tid & 15) * 8;
    // compute microtile
    const int tm = (tid >> 4) * 8;
    const int tn = (tid & 15) * 8;

    float acc[8][8];
#pragma unroll
    for (int r = 0; r < 8; ++r)
#pragma unroll
        for (int c = 0; c < 8; ++c) acc[r][c] = 0.f;

    const float* Arow = A + (m0 + rowA) * K + kcA;
    const float* Brow = W1 + (size_t)kB * N + n0 + ncB;

    for (int k0 = 0; k0 < K; k0 += BK) {
        float4 a0  = *reinterpret_cast<const float4*>(Arow + k0);
        float4 a1  = *reinterpret_cast<const float4*>(Arow + k0 + 4);
        float4 bq0 = *reinterpret_cast<const float4*>(Brow + (size_t)k0 * N);
        float4 bq1 = *reinterpret_cast<const float4*>(Brow + (size_t)k0 * N + 4);

        As[kcA + 0][rowA] = a0.x; As[kcA + 1][rowA] = a0.y;
        As[kcA + 2][rowA] = a0.z; As[kcA + 3][rowA] = a0.w;
        As[kcA + 4][rowA] = a1.x; As[kcA + 5][rowA] = a1.y;
        As[kcA + 6][rowA] = a1.z; As[kcA + 7][rowA] = a1.w;
        *reinterpret_cast<float4*>(&Bs[kB][ncB])     = bq0;
        *reinterpret_cast<float4*>(&Bs[kB][ncB + 4]) = bq1;
        __syncthreads();

#pragma unroll
        for (int kk = 0; kk < BK; ++kk) {
            float4 af0 = *reinterpret_cast<const float4*>(&As[kk][tm]);
            float4 af1 = *reinterpret_cast<const float4*>(&As[kk][tm + 4]);
            float4 bf0 = *reinterpret_cast<const float4*>(&Bs[kk][tn]);
            float4 bf1 = *reinterpret_cast<const float4*>(&Bs[kk][tn + 4]);
            float af[8] = {af0.x, af0.y, af0.z, af0.w, af1.x, af1.y, af1.z, af1.w};
            float bf[8] = {bf0.x, bf0.y, bf0.z, bf0.w, bf1.x, bf1.y, bf1.z, bf1.w};
#pragma unroll
            for (int r = 0; r < 8; ++r)
#pragma unroll
                for (int c = 0; c < 8; ++c)
                    acc[r][c] = fmaf(af[r], bf[c], acc[r][c]);
        }
        __syncthreads();
    }

    float4 bv0 = *reinterpret_cast<const float4*>(&b1[n0 + tn]);
    float4 bv1 = *reinterpret_cast<const float4*>(&b1[n0 + tn + 4]);
    float bb[8] = {bv0.x, bv0.y, bv0.z, bv0.w, bv1.x, bv1.y, bv1.z, bv1.w};
#pragma unroll
    for (int r = 0; r < 8; ++r) {
        float4 o0, o1;
        o0.x = acc[r][0] + bb[0]; o0.y = acc[r][1] + bb[1];
        o0.z = acc[r][2] + bb[2]; o0.w = acc[r][3] + bb[3];
        o1.x = acc[r][4] + bb[4]; o1.y = acc[r][5] + bb[5];
        o1.z = acc[r][6] + bb[6]; o1.w = acc[r][7] + bb[7];
        float* Crow = G + (m0 + tm + r) * N + n0 + tn;
        *reinterpret_cast<float4*>(Crow)     = o0;
        *reinterpret_cast<float4*>(Crow + 4) = o1;
    }
}

// ---------------------------------------------------------------------------
// Kernel 2: sequential greedy decode. One block per batch (no inter-block
// deps: feedback is per-batch). 1024 threads = (og 0..3) x (j 0..255).
//   thread owns o-cols [og*8, og*8+8) and h-chunk [j*8, j*8+8)
//   W2 slice (8h x 8o = 64 floats) stays in registers for the whole scan.
// ---------------------------------------------------------------------------
__global__ __launch_bounds__(1024) void seq_scan(const float* __restrict__ G,
                                                 const float* __restrict__ W1,
                                                 const float* __restrict__ W2,
                                                 const float* __restrict__ b2,
                                                 float* __restrict__ out_logits,
                                                 float* __restrict__ out_preds)
{
    const int b   = blockIdx.x;
    const int t   = threadIdx.x;       // 0..1023
    const int og  = t >> 8;            // 0..3
    const int j   = t & 255;           // 0..255
    const int o0  = og * 8;
    const int h0  = j * 8;

    __shared__ float hbuf[HID];        // 8 KB
    __shared__ float partials[16][8];  // per-wave partial logits
    __shared__ int   pred_sh;

    // W2 register slice: w2r[i][c] = W2[h0+i][o0+c]
    float w2r[8][8];
#pragma unroll
    for (int i = 0; i < 8; ++i) {
        const float4* p4 = reinterpret_cast<const float4*>(&W2[(size_t)(h0 + i) * NOUT + o0]);
        float4 aa = p4[0], bbq = p4[1];
        w2r[i][0] = aa.x;  w2r[i][1] = aa.y;  w2r[i][2] = aa.z;  w2r[i][3] = aa.w;
        w2r[i][4] = bbq.x; w2r[i][5] = bbq.y; w2r[i][6] = bbq.z; w2r[i][7] = bbq.w;
    }

    int p = 0;  // class 0 at t=0 (matches zero-init preds)
    const float* Gb = G + (size_t)b * SEQ * HID;
    // prefetch G for step 0: this thread's two h-elements (h = 2t, 2t+1)
    float2 g = *reinterpret_cast<const float2*>(Gb + 2 * t);

    for (int step = 0; step < SEQ; ++step) {
        // feedback row W1[DIM + p]
        float2 u = *reinterpret_cast<const float2*>(&W1[(size_t)(DIM + p) * HID + 2 * t]);
        float hv0 = tanhf(g.x + u.x);
        float hv1 = tanhf(g.y + u.y);
        // prefetch next step's G while phase2 runs
        if (step + 1 < SEQ)
            g = *reinterpret_cast<const float2*>(Gb + (size_t)(step + 1) * HID + 2 * t);

        *reinterpret_cast<float2*>(&hbuf[2 * t]) = make_float2(hv0, hv1);
        __syncthreads();

        // phase 2: partial logits over this thread's h-chunk
        float4 ha = *reinterpret_cast<const float4*>(&hbuf[h0]);
        float4 hb = *reinterpret_cast<const float4*>(&hbuf[h0 + 4]);
        float hv[8] = {ha.x, ha.y, ha.z, ha.w, hb.x, hb.y, hb.z, hb.w};
        float acc[8];
#pragma unroll
        for (int c = 0; c < 8; ++c) acc[c] = 0.f;
#pragma unroll
        for (int i = 0; i < 8; ++i)
#pragma unroll
            for (int c = 0; c < 8; ++c)
                acc[c] = fmaf(hv[i], w2r[i][c], acc[c]);

        // reduce across the 64 lanes of each wave (lanes of a wave share og)
#pragma unroll
        for (int off = 32; off; off >>= 1)
#pragma unroll
            for (int c = 0; c < 8; ++c)
                acc[c] += __shfl_xor(acc[c], off, 64);

        const int wave = t >> 6;   // 0..15 ; waves og*4 .. og*4+3 share og
        const int lane = t & 63;
        if (lane == 0) {
#pragma unroll
            for (int c = 0; c < 8; ++c) partials[wave][c] = acc[c];
        }
        __syncthreads();

        if (t < 32) {
            const int o  = t;
            const int gq = o >> 3;   // og
            const int c  = o & 7;
            float logit = b2[o] + partials[gq * 4 + 0][c] + partials[gq * 4 + 1][c]
                                + partials[gq * 4 + 2][c] + partials[gq * 4 + 3][c];
            out_logits[((size_t)b * SEQ + step) * NOUT + o] = logit;

            // argmax with first-max tie-break (matches jnp.argmax)
            float v = logit; int idx = o;
#pragma unroll
            for (int off = 16; off; off >>= 1) {
                float ov = __shfl_xor(v, off, 32);
                int   oi = __shfl_xor(idx, off, 32);
                if (ov > v || (ov == v && oi < idx)) { v = ov; idx = oi; }
            }
            if (o == 0) {
                pred_sh = idx;
                out_preds[(size_t)b * SEQ + step] = (float)idx;
            }
        }
        __syncthreads();
        p = pred_sh;
    }
}

// ---------------------------------------------------------------------------
extern "C" void kernel_launch(void* const* d_in, const int* in_sizes, int n_in,
                              void* d_out, int out_size, void* d_ws, size_t ws_size,
                              hipStream_t stream) {
    const float* x  = (const float*)d_in[0];   // [256,512,1024]
    const float* W1 = (const float*)d_in[1];   // [1056,2048]
    const float* b1 = (const float*)d_in[2];   // [2048]
    const float* W2 = (const float*)d_in[3];   // [2048,32]
    const float* b2 = (const float*)d_in[4];   // [32]

    float* G = (float*)d_ws;                               // [131072, 2048] fp32 = 1 GiB
    float* out_logits = (float*)d_out;                     // [256,512,32]
    float* out_preds  = (float*)d_out + (size_t)BATCH * SEQ * NOUT;  // [256,512] as float

    dim3 grid1(BATCH * SEQ / BM, HID / BN);  // 1024 x 16
    gemm_g<<<grid1, 256, 0, stream>>>(x, W1, b1, G);
    seq_scan<<<BATCH, 1024, 0, stream>>>(G, W1, W2, b2, out_logits, out_preds);
}

// Round 2
// 4589.466 us; speedup vs baseline: 1.9064x; 1.9064x over previous
//
#include <hip/hip_runtime.h>
#include <cstdint>
#include <cstddef>

#define BATCH 256
#define SEQ   512
#define DIM   1024
#define HID   2048
#define NOUT  32

typedef __attribute__((ext_vector_type(8))) short  short8;
typedef __attribute__((ext_vector_type(4))) float  f32x4;

__device__ __forceinline__ ushort f2bf(float v) {
    uint u = __builtin_bit_cast(uint, v);
    u = u + 0x7FFFu + ((u >> 16) & 1u);     // round-to-nearest-even
    return (ushort)(u >> 16);
}
__device__ __forceinline__ float bf2f(ushort h) {
    uint u = ((uint)h) << 16;
    return __builtin_bit_cast(float, u);
}

// ---------------------------------------------------------------------------
// Prep: W1[:DIM] (fp32, [K=1024][N=2048]) -> Bt_hi/Bt_lo (bf16, [N][K])
// 32x32 LDS tiled transpose + hi/lo split.
// ---------------------------------------------------------------------------
__global__ __launch_bounds__(256) void split_w1t(const float* __restrict__ W1,
                                                 ushort* __restrict__ Bth,
                                                 ushort* __restrict__ Btl)
{
    __shared__ ushort th[32][33];
    __shared__ ushort tl[32][33];
    const int n0 = blockIdx.x * 32;
    const int k0 = blockIdx.y * 32;
    const int tx = threadIdx.x & 31;
    const int ty = threadIdx.x >> 5;     // 0..7
#pragma unroll
    for (int r = 0; r < 4; ++r) {
        int k = ty + r * 8;
        float v = W1[(size_t)(k0 + k) * HID + n0 + tx];
        ushort h = f2bf(v);
        th[k][tx] = h;
        tl[k][tx] = f2bf(v - bf2f(h));
    }
    __syncthreads();
#pragma unroll
    for (int r = 0; r < 4; ++r) {
        int n = ty + r * 8;              // row of output
        Bth[(size_t)(n0 + n) * DIM + k0 + tx] = th[tx][n];
        Btl[(size_t)(n0 + n) * DIM + k0 + tx] = tl[tx][n];
    }
}

// ---------------------------------------------------------------------------
// Kernel 1: G = x @ W1[:DIM] + b1 via split-bf16 MFMA (3 products: hh+hl+lh).
// M=131072, K=1024, N=2048. 128x128 tile, BK=32, 256 thr = 4 waves,
// wave tile 64x64 = 4x4 of mfma_f32_16x16x32_bf16. fp32 accumulation.
// ---------------------------------------------------------------------------
#define BM 128
#define BN 128
#define BK 32

__global__ __launch_bounds__(256) void gemm_split(const float*  __restrict__ A,
                                                  const ushort* __restrict__ Bth,
                                                  const ushort* __restrict__ Btl,
                                                  const float*  __restrict__ b1,
                                                  float* __restrict__ G)
{
    __shared__ ushort Ah[BM][BK];
    __shared__ ushort Al[BM][BK];
    __shared__ ushort Bh[BN][BK];
    __shared__ ushort Bl[BN][BK];

    const int tid  = threadIdx.x;
    const int lane = tid & 63;
    const int wave = tid >> 6;
    const int n0 = blockIdx.x * BN;     // x = n-tiles so A-tile is L2/LLC-shared
    const int m0 = blockIdx.y * BM;
    const int wm = (wave & 1) * 64;
    const int wn = (wave >> 1) * 64;

    // staging: 2 threads per row, 16 elements each
    const int srow = tid >> 1;
    const int skc  = (tid & 1) * 16;
    const float*  aptr  = A   + (size_t)(m0 + srow) * DIM + skc;
    const ushort* bhptr = Bth + (size_t)(n0 + srow) * DIM + skc;
    const ushort* blptr = Btl + (size_t)(n0 + srow) * DIM + skc;

    // fragment coords (16x16x32: m/n = lane&15, k-chunk = (lane>>4)*8)
    const int fr = lane & 15;
    const int fq = lane >> 4;

    f32x4 acc[4][4];
#pragma unroll
    for (int i = 0; i < 4; ++i)
#pragma unroll
        for (int j = 0; j < 4; ++j) {
            f32x4 z = {0.f, 0.f, 0.f, 0.f};
            acc[i][j] = z;
        }

    for (int k0 = 0; k0 < DIM; k0 += BK) {
        // global loads (VGPR) for this iteration
        float4 a0 = *(const float4*)(aptr + k0);
        float4 a1 = *(const float4*)(aptr + k0 + 4);
        float4 a2 = *(const float4*)(aptr + k0 + 8);
        float4 a3 = *(const float4*)(aptr + k0 + 12);
        short8 bh0 = *(const short8*)(bhptr + k0);
        short8 bh1 = *(const short8*)(bhptr + k0 + 8);
        short8 bl0 = *(const short8*)(blptr + k0);
        short8 bl1 = *(const short8*)(blptr + k0 + 8);

        __syncthreads();   // previous iteration's fragment reads complete

        float av[16] = {a0.x, a0.y, a0.z, a0.w, a1.x, a1.y, a1.z, a1.w,
                        a2.x, a2.y, a2.z, a2.w, a3.x, a3.y, a3.z, a3.w};
        short8 h0, h1, l0, l1;
#pragma unroll
        for (int i = 0; i < 8; ++i) {
            ushort h = f2bf(av[i]);
            h0[i] = (short)h;
            l0[i] = (short)f2bf(av[i] - bf2f(h));
        }
#pragma unroll
        for (int i = 0; i < 8; ++i) {
            ushort h = f2bf(av[8 + i]);
            h1[i] = (short)h;
            l1[i] = (short)f2bf(av[8 + i] - bf2f(h));
        }
        *(short8*)&Ah[srow][skc]     = h0;
        *(short8*)&Ah[srow][skc + 8] = h1;
        *(short8*)&Al[srow][skc]     = l0;
        *(short8*)&Al[srow][skc + 8] = l1;
        *(short8*)&Bh[srow][skc]     = bh0;
        *(short8*)&Bh[srow][skc + 8] = bh1;
        *(short8*)&Bl[srow][skc]     = bl0;
        *(short8*)&Bl[srow][skc + 8] = bl1;

        __syncthreads();

        short8 afh[4], afl[4], bfh[4], bfl[4];
#pragma unroll
        for (int t = 0; t < 4; ++t) {
            afh[t] = *(const short8*)&Ah[wm + t * 16 + fr][fq * 8];
            afl[t] = *(const short8*)&Al[wm + t * 16 + fr][fq * 8];
            bfh[t] = *(const short8*)&Bh[wn + t * 16 + fr][fq * 8];
            bfl[t] = *(const short8*)&Bl[wn + t * 16 + fr][fq * 8];
        }
#pragma unroll
        for (int mt = 0; mt < 4; ++mt)
#pragma unroll
            for (int nt = 0; nt < 4; ++nt) {
                acc[mt][nt] = __builtin_amdgcn_mfma_f32_16x16x32_bf16(afh[mt], bfh[nt], acc[mt][nt], 0, 0, 0);
                acc[mt][nt] = __builtin_amdgcn_mfma_f32_16x16x32_bf16(afh[mt], bfl[nt], acc[mt][nt], 0, 0, 0);
                acc[mt][nt] = __builtin_amdgcn_mfma_f32_16x16x32_bf16(afl[mt], bfh[nt], acc[mt][nt], 0, 0, 0);
            }
    }

    // epilogue: C/D layout col = lane&15, row = (lane>>4)*4 + reg
#pragma unroll
    for (int nt = 0; nt < 4; ++nt) {
        const int gn = n0 + wn + nt * 16 + fr;
        const float bias = b1[gn];
#pragma unroll
        for (int mt = 0; mt < 4; ++mt) {
            const int gmb = m0 + wm + mt * 16 + fq * 4;
            float* out = G + (size_t)gmb * HID + gn;
#pragma unroll
            for (int r = 0; r < 4; ++r)
                out[(size_t)r * HID] = acc[mt][nt][r] + bias;
        }
    }
}

// ---------------------------------------------------------------------------
// Kernel 2: sequential greedy decode (unchanged from passing round 1).
// ---------------------------------------------------------------------------
__global__ __launch_bounds__(1024) void seq_scan(const float* __restrict__ G,
                                                 const float* __restrict__ W1,
                                                 const float* __restrict__ W2,
                                                 const float* __restrict__ b2,
                                                 float* __restrict__ out_logits,
                                                 float* __restrict__ out_preds)
{
    const int b   = blockIdx.x;
    const int t   = threadIdx.x;
    const int og  = t >> 8;
    const int j   = t & 255;
    const int o0  = og * 8;
    const int h0  = j * 8;

    __shared__ float hbuf[HID];
    __shared__ float partials[16][8];
    __shared__ int   pred_sh;

    float w2r[8][8];
#pragma unroll
    for (int i = 0; i < 8; ++i) {
        const float4* p4 = reinterpret_cast<const float4*>(&W2[(size_t)(h0 + i) * NOUT + o0]);
        float4 aa = p4[0], bbq = p4[1];
        w2r[i][0] = aa.x;  w2r[i][1] = aa.y;  w2r[i][2] = aa.z;  w2r[i][3] = aa.w;
        w2r[i][4] = bbq.x; w2r[i][5] = bbq.y; w2r[i][6] = bbq.z; w2r[i][7] = bbq.w;
    }

    int p = 0;
    const float* Gb = G + (size_t)b * SEQ * HID;
    float2 g = *reinterpret_cast<const float2*>(Gb + 2 * t);

    for (int step = 0; step < SEQ; ++step) {
        float2 u = *reinterpret_cast<const float2*>(&W1[(size_t)(DIM + p) * HID + 2 * t]);
        float hv0 = tanhf(g.x + u.x);
        float hv1 = tanhf(g.y + u.y);
        if (step + 1 < SEQ)
            g = *reinterpret_cast<const float2*>(Gb + (size_t)(step + 1) * HID + 2 * t);

        *reinterpret_cast<float2*>(&hbuf[2 * t]) = make_float2(hv0, hv1);
        __syncthreads();

        float4 ha = *reinterpret_cast<const float4*>(&hbuf[h0]);
        float4 hb = *reinterpret_cast<const float4*>(&hbuf[h0 + 4]);
        float hv[8] = {ha.x, ha.y, ha.z, ha.w, hb.x, hb.y, hb.z, hb.w};
        float acc[8];
#pragma unroll
        for (int c = 0; c < 8; ++c) acc[c] = 0.f;
#pragma unroll
        for (int i = 0; i < 8; ++i)
#pragma unroll
            for (int c = 0; c < 8; ++c)
                acc[c] = fmaf(hv[i], w2r[i][c], acc[c]);

#pragma unroll
        for (int off = 32; off; off >>= 1)
#pragma unroll
            for (int c = 0; c < 8; ++c)
                acc[c] += __shfl_xor(acc[c], off, 64);

        const int wave = t >> 6;
        const int lane = t & 63;
        if (lane == 0) {
#pragma unroll
            for (int c = 0; c < 8; ++c) partials[wave][c] = acc[c];
        }
        __syncthreads();

        if (t < 32) {
            const int o  = t;
            const int gq = o >> 3;
            const int c  = o & 7;
            float logit = b2[o] + partials[gq * 4 + 0][c] + partials[gq * 4 + 1][c]
                                + partials[gq * 4 + 2][c] + partials[gq * 4 + 3][c];
            out_logits[((size_t)b * SEQ + step) * NOUT + o] = logit;

            float v = logit; int idx = o;
#pragma unroll
            for (int off = 16; off; off >>= 1) {
                float ov = __shfl_xor(v, off, 32);
                int   oi = __shfl_xor(idx, off, 32);
                if (ov > v || (ov == v && oi < idx)) { v = ov; idx = oi; }
            }
            if (o == 0) {
                pred_sh = idx;
                out_preds[(size_t)b * SEQ + step] = (float)idx;
            }
        }
        __syncthreads();
        p = pred_sh;
    }
}

// ---------------------------------------------------------------------------
extern "C" void kernel_launch(void* const* d_in, const int* in_sizes, int n_in,
                              void* d_out, int out_size, void* d_ws, size_t ws_size,
                              hipStream_t stream) {
    const float* x  = (const float*)d_in[0];   // [256,512,1024]
    const float* W1 = (const float*)d_in[1];   // [1056,2048]
    const float* b1 = (const float*)d_in[2];   // [2048]
    const float* W2 = (const float*)d_in[3];   // [2048,32]
    const float* b2 = (const float*)d_in[4];   // [32]

    const size_t G_ELEMS = (size_t)BATCH * SEQ * HID;          // 268M fp32 = 1 GiB
    float*  G   = (float*)d_ws;
    ushort* Bth = (ushort*)((char*)d_ws + G_ELEMS * sizeof(float));
    ushort* Btl = Bth + (size_t)HID * DIM;                     // 4 MB each

    float* out_logits = (float*)d_out;
    float* out_preds  = (float*)d_out + (size_t)BATCH * SEQ * NOUT;

    split_w1t<<<dim3(HID / 32, DIM / 32), 256, 0, stream>>>(W1, Bth, Btl);
    gemm_split<<<dim3(HID / BN, BATCH * SEQ / BM), 256, 0, stream>>>(x, Bth, Btl, b1, G);
    seq_scan<<<BATCH, 1024, 0, stream>>>(G, W1, W2, b2, out_logits, out_preds);
}